// Round 1
// baseline (1127.604 us; speedup 1.0000x reference)
//
#include <hip/hip_runtime.h>
#include <hip/hip_bf16.h>
#include <math.h>

#define B_  2
#define L_  512
#define D_  512
#define H_  16
#define P_  128
#define NL_ 2
#define DH_ 32
#define FF_ 2048
#define NT_ (B_*L_)

__device__ __forceinline__ float siluf(float x){ return x / (1.f + expf(-x)); }
__device__ __forceinline__ float geluf(float x){
  const float c = 0.7978845608028654f;  // sqrt(2/pi)
  float x3 = x*x*x;
  return 0.5f*x*(1.f + tanhf(c*(x + 0.044715f*x3)));
}

// ---------------- pos embedding + keep mask ----------------
__global__ __launch_bounds__(256) void k_posemb(const float* __restrict__ pos,
      const float* __restrict__ w, const int* __restrict__ maskp,
      float* __restrict__ h, float* __restrict__ keepf){
  int n = blockIdx.x;                       // b*L + l
  float kf = (maskp[n] != 0) ? 0.f : 1.f;   // True = pad
  if (threadIdx.x == 0) keepf[n] = kf;
  float p0 = pos[n*3+0], p1 = pos[n*3+1], p2 = pos[n*3+2];
  for (int d = threadIdx.x; d < D_; d += 256){
    float v = p0*w[d*3+0] + p1*w[d*3+1] + p2*w[d*3+2];
    h[(size_t)n*D_ + d] = kf*v;
  }
}

// ---------------- pair bias: pfb[b,h,l,m] = sum_p silu(pair[b,l,m,p]) * w[h,p] ----------------
__global__ __launch_bounds__(64) void k_pfb(const float* __restrict__ pair,
      const float* __restrict__ w, float* __restrict__ pfb){
  int blk = blockIdx.x;
  int mc = blk & 7;           // m-chunk of 64
  int n  = blk >> 3;          // b*L + l
  int b = n >> 9, l = n & 511;
  __shared__ float sp[64][128];
  __shared__ float sw[16][128];
  int tid = threadIdx.x;
  for (int idx = tid; idx < 512; idx += 64){          // 16x128 weights
    int hh = idx >> 5, c4 = idx & 31;
    float4 v = ((const float4*)w)[idx];
    *(float4*)&sw[hh][4*(c4 ^ (hh & 7))] = v;         // xor-swizzled columns
  }
  const float* base = pair + (((size_t)n)*512 + mc*64)*128;
  for (int idx = tid; idx < 2048; idx += 64){         // 64x128 pair chunk, silu on the fly
    int mm = idx >> 5, c4 = idx & 31;
    float4 v = ((const float4*)base)[idx];
    v.x = siluf(v.x); v.y = siluf(v.y); v.z = siluf(v.z); v.w = siluf(v.w);
    *(float4*)&sp[mm][4*(c4 ^ (mm & 7))] = v;
  }
  __syncthreads();
  int mq = tid & 15, hq = tid >> 4;   // thread owns m = mq+16i, h = hq+4j
  float acc[4][4] = {};
  for (int c4 = 0; c4 < 32; ++c4){
    float4 a[4], wv[4];
    #pragma unroll
    for (int i = 0; i < 4; ++i)
      a[i] = *(const float4*)&sp[mq + 16*i][4*(c4 ^ (mq & 7))];
    #pragma unroll
    for (int j = 0; j < 4; ++j)
      wv[j] = *(const float4*)&sw[hq + 4*j][4*(c4 ^ ((hq + 4*j) & 7))];
    #pragma unroll
    for (int i = 0; i < 4; ++i)
      #pragma unroll
      for (int j = 0; j < 4; ++j)
        acc[i][j] += a[i].x*wv[j].x + a[i].y*wv[j].y + a[i].z*wv[j].z + a[i].w*wv[j].w;
  }
  #pragma unroll
  for (int j = 0; j < 4; ++j){
    int hh = hq + 4*j;
    #pragma unroll
    for (int i = 0; i < 4; ++i){
      int m = mc*64 + mq + 16*i;
      pfb[(((size_t)(b*16 + hh))*512 + l)*512 + m] = acc[i][j];
    }
  }
}

// ---------------- colmean[b,m,l] = mean_h pfb[b,h,l,m] ----------------
__global__ __launch_bounds__(256) void k_colmean(const float* __restrict__ pfb,
      float* __restrict__ colm){
  int n = blockIdx.x; int b = n >> 9, l = n & 511;
  int m1 = threadIdx.x, m2 = threadIdx.x + 256;
  float a0 = 0.f, a1 = 0.f;
  for (int hh = 0; hh < 16; ++hh){
    const float* row = pfb + (((size_t)(b*16 + hh))*512 + l)*512;
    a0 += row[m1]; a1 += row[m2];
  }
  colm[((size_t)(b*512 + m1))*512 + l] = a0 * (1.f/16.f);
  colm[((size_t)(b*512 + m2))*512 + l] = a1 * (1.f/16.f);
}

// ---------------- top-3 rows per column + pair2node MLP + cond = silu(x + f2n) ----------------
__global__ __launch_bounds__(128) void k_topk_f2n(const float* __restrict__ colm,
      const float* __restrict__ pair, const float* __restrict__ keepf,
      const float* __restrict__ w1, const float* __restrict__ w2,
      const float* __restrict__ xin, float* __restrict__ cond){
  int n = blockIdx.x; int b = n >> 9, m = n & 511;
  __shared__ int sidx[3];
  __shared__ float f2n_s[128];
  __shared__ float u_s[128];
  int tid = threadIdx.x;
  if (tid < 64){
    const float* col = colm + (size_t)n*512;
    float v[8];
    #pragma unroll
    for (int i = 0; i < 8; ++i) v[i] = col[tid + 64*i];
    int c0 = -1, c1 = -1;
    for (int r = 0; r < 3; ++r){
      float bv = -INFINITY; int bi = 1 << 30;
      #pragma unroll
      for (int i = 0; i < 8; ++i){
        int idx = tid + 64*i;
        bool excl = (idx == c0) || (idx == c1);
        float val = v[i];
        if (!excl && (val > bv || (val == bv && idx < bi))){ bv = val; bi = idx; }
      }
      for (int o = 32; o > 0; o >>= 1){     // wave argmax, tie -> lower index
        float ov = __shfl_down(bv, o);
        int   oi = __shfl_down(bi, o);
        if (ov > bv || (ov == bv && oi < bi)){ bv = ov; bi = oi; }
      }
      bi = __shfl(bi, 0);
      if (tid == 0) sidx[r] = bi;
      if (r == 0) c0 = bi; else c1 = bi;
    }
  }
  __syncthreads();
  int i0 = sidx[0], i1 = sidx[1], i2 = sidx[2];
  float kc = keepf[n];
  float k0 = keepf[b*512 + i0], k1 = keepf[b*512 + i1], k2 = keepf[b*512 + i2];
  {
    int p = tid;
    float s = k0*pair[(((size_t)(b*512 + i0))*512 + m)*128 + p]
            + k1*pair[(((size_t)(b*512 + i1))*512 + m)*128 + p]
            + k2*pair[(((size_t)(b*512 + i2))*512 + m)*128 + p];
    f2n_s[p] = s * kc * (1.f/3.f);
  }
  __syncthreads();
  {
    int j = tid;
    const float* wr = w1 + (size_t)j*128;
    float acc = 0.f;
    #pragma unroll 8
    for (int p = 0; p < 128; ++p) acc += f2n_s[p]*wr[p];
    u_s[j] = siluf(acc);
  }
  __syncthreads();
  for (int d = tid; d < 512; d += 128){
    const float* wr = w2 + (size_t)d*128;
    float acc = 0.f;
    #pragma unroll 8
    for (int p = 0; p < 128; ++p) acc += u_s[p]*wr[p];
    float xv = xin[((size_t)(m*2 + b))*512 + d];     // x is [L,B,D]
    cond[(size_t)n*512 + d] = siluf(xv + acc);
  }
}

// ---------------- hin = h + time_emb ----------------
__global__ __launch_bounds__(128) void k_addte(const float* __restrict__ h,
      const float* __restrict__ te, float* __restrict__ hin){
  int n = blockIdx.x; int b = n >> 9;
  int tid = threadIdx.x;
  float4 v = ((const float4*)(h  + (size_t)n*512))[tid];
  float4 t = ((const float4*)(te + (size_t)b*512))[tid];
  v.x += t.x; v.y += t.y; v.z += t.z; v.w += t.w;
  ((float4*)(hin + (size_t)n*512))[tid] = v;
}

// ---------------- LayerNorm + adaLN modulate ----------------
__global__ __launch_bounds__(128) void k_lnmod(const float* __restrict__ hin,
      const float* __restrict__ mod, float* __restrict__ out, int sh_off, int sc_off){
  int n = blockIdx.x;
  int tid = threadIdx.x;
  float4 v = ((const float4*)(hin + (size_t)n*512))[tid];
  float s = v.x + v.y + v.z + v.w;
  float q = v.x*v.x + v.y*v.y + v.z*v.z + v.w*v.w;
  #pragma unroll
  for (int o = 1; o < 64; o <<= 1){ s += __shfl_xor(s, o); q += __shfl_xor(q, o); }
  __shared__ float s2[2], q2[2];
  if ((tid & 63) == 0){ s2[tid >> 6] = s; q2[tid >> 6] = q; }
  __syncthreads();
  float S = s2[0] + s2[1], Q = q2[0] + q2[1];
  float mean = S * (1.f/512.f);
  float var  = Q * (1.f/512.f) - mean*mean;
  float rstd = rsqrtf(var + 1e-5f);
  const float* mrow = mod + (size_t)n*3072;
  float4 sc = *(const float4*)(mrow + sc_off + tid*4);
  float4 sh = *(const float4*)(mrow + sh_off + tid*4);
  float4 rv;
  rv.x = (v.x - mean)*rstd*(1.f + sc.x) + sh.x;
  rv.y = (v.y - mean)*rstd*(1.f + sc.y) + sh.y;
  rv.z = (v.z - mean)*rstd*(1.f + sc.z) + sh.z;
  rv.w = (v.w - mean)*rstd*(1.f + sc.w) + sh.w;
  ((float4*)(out + (size_t)n*512))[tid] = rv;
}

// ---------------- generic f32 GEMM: C[M,N] = epi(A[M,K] @ Bw[N,K]^T + bias) ----------------
// epi: 0 none, 1 res + gate*val, 2 gelu
__global__ __launch_bounds__(256) void k_gemm(const float* __restrict__ A,
      const float* __restrict__ Bw, const float* __restrict__ bias,
      float* __restrict__ C, int M, int N, int K, int epi,
      const float* __restrict__ res, const float* __restrict__ gate, int gate_ld){
  __shared__ float As[16][68];
  __shared__ float Bs[16][68];
  int tid = threadIdx.x;
  int tx = tid & 15, ty = tid >> 4;
  int m0 = blockIdx.y * 64, n0 = blockIdx.x * 64;
  int arow = tid >> 2, ak = (tid & 3)*4;
  const float* Aptr = A  + (size_t)(m0 + arow)*K + ak;
  const float* Bptr = Bw + (size_t)(n0 + arow)*K + ak;
  float acc[4][4] = {};
  for (int k0 = 0; k0 < K; k0 += 16){
    float4 a4 = *(const float4*)(Aptr + k0);
    float4 b4 = *(const float4*)(Bptr + k0);
    __syncthreads();
    As[ak+0][arow] = a4.x; As[ak+1][arow] = a4.y; As[ak+2][arow] = a4.z; As[ak+3][arow] = a4.w;
    Bs[ak+0][arow] = b4.x; Bs[ak+1][arow] = b4.y; Bs[ak+2][arow] = b4.z; Bs[ak+3][arow] = b4.w;
    __syncthreads();
    #pragma unroll
    for (int kk = 0; kk < 16; ++kk){
      float4 av = *(const float4*)&As[kk][ty*4];
      float4 bv = *(const float4*)&Bs[kk][tx*4];
      acc[0][0] += av.x*bv.x; acc[0][1] += av.x*bv.y; acc[0][2] += av.x*bv.z; acc[0][3] += av.x*bv.w;
      acc[1][0] += av.y*bv.x; acc[1][1] += av.y*bv.y; acc[1][2] += av.y*bv.z; acc[1][3] += av.y*bv.w;
      acc[2][0] += av.z*bv.x; acc[2][1] += av.z*bv.y; acc[2][2] += av.z*bv.z; acc[2][3] += av.z*bv.w;
      acc[3][0] += av.w*bv.x; acc[3][1] += av.w*bv.y; acc[3][2] += av.w*bv.z; acc[3][3] += av.w*bv.w;
    }
  }
  float4 bv4 = *(const float4*)(bias + n0 + tx*4);
  float bb[4] = {bv4.x, bv4.y, bv4.z, bv4.w};
  #pragma unroll
  for (int i = 0; i < 4; ++i){
    int row = m0 + ty*4 + i;
    float4 v;
    v.x = acc[i][0] + bb[0];
    v.y = acc[i][1] + bb[1];
    v.z = acc[i][2] + bb[2];
    v.w = acc[i][3] + bb[3];
    if (epi == 1){
      float4 rv = *(const float4*)(res  + (size_t)row*N       + n0 + tx*4);
      float4 gv = *(const float4*)(gate + (size_t)row*gate_ld + n0 + tx*4);
      v.x = rv.x + gv.x*v.x; v.y = rv.y + gv.y*v.y; v.z = rv.z + gv.z*v.z; v.w = rv.w + gv.w*v.w;
    } else if (epi == 2){
      v.x = geluf(v.x); v.y = geluf(v.y); v.z = geluf(v.z); v.w = geluf(v.w);
    }
    *(float4*)(C + (size_t)row*N + n0 + tx*4) = v;
  }
}

// ---------------- attention: per (b,h), 16 q-rows per block ----------------
__global__ __launch_bounds__(256) void k_attn(const float* __restrict__ qkv,
      const float* __restrict__ pfb, const float* __restrict__ keepf,
      float* __restrict__ obuf){
  int blk = blockIdx.x;
  int tile = blk & 31;       // L/16 tiles
  int bh = blk >> 5;         // b*16 + h
  int b = bh >> 4;
  int r0 = tile*16;
  int hbase = (bh & 15)*32;
  __shared__ float qs[16][36];
  __shared__ float ks[64][36];
  __shared__ float ss[16][516];
  __shared__ float inv_s[16];
  int tid = threadIdx.x;
  {
    int idx = tid;
    #pragma unroll
    for (int i = 0; i < 2; ++i, idx += 256){
      int r = idx >> 5, dh = idx & 31;
      qs[r][dh] = qkv[((size_t)(b*512 + r0 + r))*1536 + hbase + dh];
    }
  }
  const float scale = 0.17677669529663687f;  // 1/sqrt(32)
  int r = tid >> 4, mo = tid & 15;
  for (int mc = 0; mc < 8; ++mc){
    __syncthreads();
    {
      int idx = tid;
      #pragma unroll
      for (int i = 0; i < 8; ++i, idx += 256){
        int ml = idx >> 5, dh = idx & 31;
        ks[ml][dh] = qkv[((size_t)(b*512 + mc*64 + ml))*1536 + 512 + hbase + dh];
      }
    }
    __syncthreads();
    const float4* qrow = (const float4*)&qs[r][0];
    #pragma unroll
    for (int j = 0; j < 4; ++j){
      int ml = mo + 16*j;
      const float4* krow = (const float4*)&ks[ml][0];
      float acc = 0.f;
      #pragma unroll
      for (int t = 0; t < 8; ++t){
        float4 qa = qrow[t], ka = krow[t];
        acc += qa.x*ka.x + qa.y*ka.y + qa.z*ka.z + qa.w*ka.w;
      }
      int m = mc*64 + ml;
      float sv = acc*scale + pfb[((size_t)bh*512 + (r0 + r))*512 + m];
      if (keepf[b*512 + m] == 0.f) sv = -1e9f;
      ss[r][m] = sv;
    }
  }
  // softmax: row r is owned by 16 lanes of one wave (tid>>4) -> wave-local, no barrier needed
  {
    float mx = -INFINITY;
    for (int t = 0; t < 32; ++t) mx = fmaxf(mx, ss[r][mo + 16*t]);
    #pragma unroll
    for (int o = 1; o < 16; o <<= 1) mx = fmaxf(mx, __shfl_xor(mx, o));
    float sum = 0.f;
    for (int t = 0; t < 32; ++t){
      int m = mo + 16*t;
      float e = expf(ss[r][m] - mx);
      ss[r][m] = e;
      sum += e;
    }
    #pragma unroll
    for (int o = 1; o < 16; o <<= 1) sum += __shfl_xor(sum, o);
    if (mo == 0) inv_s[r] = 1.f/sum;
  }
  // PV
  float acc0 = 0.f, acc1 = 0.f;
  int dho = mo;
  for (int mc = 0; mc < 8; ++mc){
    __syncthreads();
    {
      int idx = tid;
      #pragma unroll
      for (int i = 0; i < 8; ++i, idx += 256){
        int ml = idx >> 5, dh = idx & 31;
        ks[ml][dh] = qkv[((size_t)(b*512 + mc*64 + ml))*1536 + 1024 + hbase + dh];
      }
    }
    __syncthreads();
    #pragma unroll 8
    for (int ml = 0; ml < 64; ++ml){
      float p = ss[r][mc*64 + ml];
      float2 vv = *(const float2*)&ks[ml][dho*2];
      acc0 += p*vv.x; acc1 += p*vv.y;
    }
  }
  float inv = inv_s[r];
  float2 o2; o2.x = acc0*inv; o2.y = acc1*inv;
  *(float2*)(obuf + ((size_t)(b*512 + r0 + r))*512 + hbase + dho*2) = o2;
}

extern "C" void kernel_launch(void* const* d_in, const int* in_sizes, int n_in,
                              void* d_out, int out_size, void* d_ws, size_t ws_size,
                              hipStream_t stream){
  (void)in_sizes; (void)n_in; (void)out_size; (void)ws_size;
  const float* x        = (const float*)d_in[0];
  const float* pos      = (const float*)d_in[1];
  const float* time_emb = (const float*)d_in[2];
  const float* pair     = (const float*)d_in[3];
  const float* pos_w    = (const float*)d_in[4];
  const float* pfb_w    = (const float*)d_in[5];
  const float* p2n_w1   = (const float*)d_in[6];
  const float* p2n_w2   = (const float*)d_in[7];
  const float* adaln_w  = (const float*)d_in[8];
  const float* adaln_b  = (const float*)d_in[9];
  const float* qkv_w    = (const float*)d_in[10];
  const float* qkv_b    = (const float*)d_in[11];
  const float* proj_w   = (const float*)d_in[12];
  const float* proj_b   = (const float*)d_in[13];
  const float* mlp_w1   = (const float*)d_in[14];
  const float* mlp_b1   = (const float*)d_in[15];
  const float* mlp_w2   = (const float*)d_in[16];
  const float* mlp_b2   = (const float*)d_in[17];
  const int*   maskp    = (const int*)d_in[18];

  float* W = (float*)d_ws;
  size_t off = 0;
  auto alloc = [&](size_t nelem){ float* p = W + off; off += nelem; return p; };
  float* h      = alloc((size_t)NT_*D_);
  float* cond   = alloc((size_t)NT_*D_);
  float* keepf  = alloc(NT_);
  float* pfbbuf = alloc((size_t)B_*H_*L_*L_);
  float* colm   = alloc((size_t)B_*L_*L_);
  float* modb   = alloc((size_t)NT_*6*D_);
  float* qkvb   = alloc((size_t)NT_*3*D_);
  float* midb   = alloc((size_t)NT_*FF_);
  float* hin    = alloc((size_t)NT_*D_);
  float* hin2   = alloc((size_t)NT_*D_);
  float* abuf   = alloc((size_t)NT_*D_);
  float* obuf   = alloc((size_t)NT_*D_);

  k_posemb<<<NT_, 256, 0, stream>>>(pos, pos_w, maskp, h, keepf);
  k_pfb<<<NT_*8, 64, 0, stream>>>(pair, pfb_w, pfbbuf);
  k_colmean<<<NT_, 256, 0, stream>>>(pfbbuf, colm);
  k_topk_f2n<<<NT_, 128, 0, stream>>>(colm, pair, keepf, p2n_w1, p2n_w2, x, cond);

  for (int l = 0; l < NL_; ++l){
    k_addte<<<NT_, 128, 0, stream>>>(h, time_emb, hin);
    k_gemm<<<dim3(48,16), 256, 0, stream>>>(cond, adaln_w + (size_t)l*6*D_*D_,
        adaln_b + (size_t)l*6*D_, modb, NT_, 6*D_, D_, 0, nullptr, nullptr, 0);
    k_lnmod<<<NT_, 128, 0, stream>>>(hin, modb, abuf, 0, D_);
    k_gemm<<<dim3(24,16), 256, 0, stream>>>(abuf, qkv_w + (size_t)l*3*D_*D_,
        qkv_b + (size_t)l*3*D_, qkvb, NT_, 3*D_, D_, 0, nullptr, nullptr, 0);
    k_attn<<<B_*H_*(L_/16), 256, 0, stream>>>(qkvb, pfbbuf, keepf, obuf);
    k_gemm<<<dim3(8,16), 256, 0, stream>>>(obuf, proj_w + (size_t)l*D_*D_,
        proj_b + (size_t)l*D_, hin2, NT_, D_, D_, 1, hin, modb + 2*D_, 6*D_);
    k_lnmod<<<NT_, 128, 0, stream>>>(hin2, modb, abuf, 3*D_, 4*D_);
    k_gemm<<<dim3(32,16), 256, 0, stream>>>(abuf, mlp_w1 + (size_t)l*FF_*D_,
        mlp_b1 + (size_t)l*FF_, midb, NT_, FF_, D_, 2, nullptr, nullptr, 0);
    float* hout = (l == NL_-1) ? (float*)d_out : h;
    k_gemm<<<dim3(8,16), 256, 0, stream>>>(midb, mlp_w2 + (size_t)l*D_*FF_,
        mlp_b2 + (size_t)l*D_, hout, NT_, D_, FF_, 1, hin2, modb + 5*D_, 6*D_);
  }
}

// Round 2
// 639.615 us; speedup vs baseline: 1.7629x; 1.7629x over previous
//
#include <hip/hip_runtime.h>
#include <hip/hip_bf16.h>
#include <math.h>

#define B_  2
#define L_  512
#define D_  512
#define H_  16
#define P_  128
#define NL_ 2
#define DH_ 32
#define FF_ 2048
#define NT_ (B_*L_)

typedef __bf16 bf16_t;
typedef bf16_t bf16x8 __attribute__((ext_vector_type(8)));
typedef float  f32x4  __attribute__((ext_vector_type(4)));

__device__ __forceinline__ float siluf(float x){ return x / (1.f + expf(-x)); }
__device__ __forceinline__ float geluf(float x){
  const float c = 0.7978845608028654f;  // sqrt(2/pi)
  float x3 = x*x*x;
  return 0.5f*x*(1.f + tanhf(c*(x + 0.044715f*x3)));
}

// ---------------- pos embedding + keep mask ----------------
__global__ __launch_bounds__(256) void k_posemb(const float* __restrict__ pos,
      const float* __restrict__ w, const int* __restrict__ maskp,
      float* __restrict__ h, float* __restrict__ keepf){
  int n = blockIdx.x;                       // b*L + l
  float kf = (maskp[n] != 0) ? 0.f : 1.f;   // True = pad
  if (threadIdx.x == 0) keepf[n] = kf;
  float p0 = pos[n*3+0], p1 = pos[n*3+1], p2 = pos[n*3+2];
  for (int d = threadIdx.x; d < D_; d += 256){
    float v = p0*w[d*3+0] + p1*w[d*3+1] + p2*w[d*3+2];
    h[(size_t)n*D_ + d] = kf*v;
  }
}

// ---------------- pair bias fused with col-mean ----------------
// pfb[b,h,l,m] = sum_p silu(pair[b,l,m,p]) * w[h,p]
// colm[b,l,m]  = mean_h pfb[b,h,l,m]   (transposed layout, coalesced write)
__global__ __launch_bounds__(256) void k_pfb2(const float* __restrict__ pair,
      const float* __restrict__ w, float* __restrict__ pfb, float* __restrict__ colm){
  int blk = blockIdx.x;
  int mc = blk & 1;            // m half (256 each)
  int n  = blk >> 1;           // b*L + l
  int b = n >> 9, l = n & 511;
  int tid = threadIdx.x;
  __shared__ float sw[16][128];
  {
    float4* swv = (float4*)&sw[0][0];
    const float4* wv = (const float4*)w;
    swv[tid] = wv[tid];                 // 512 float4 total / 256 threads = 2
    swv[tid + 256] = wv[tid + 256];
  }
  __syncthreads();
  int m = mc*256 + tid;
  const float* rowp = pair + (((size_t)n)*512 + m)*128;
  float acc[16] = {};
  #pragma unroll 4
  for (int pc = 0; pc < 32; ++pc){
    float4 v = ((const float4*)rowp)[pc];
    v.x = siluf(v.x); v.y = siluf(v.y); v.z = siluf(v.z); v.w = siluf(v.w);
    #pragma unroll
    for (int hh = 0; hh < 16; ++hh){
      float4 wv = *(const float4*)&sw[hh][pc*4];   // wave-uniform -> broadcast
      acc[hh] += v.x*wv.x + v.y*wv.y + v.z*wv.z + v.w*wv.w;
    }
  }
  float mean = 0.f;
  #pragma unroll
  for (int hh = 0; hh < 16; ++hh) mean += acc[hh];
  colm[((size_t)n)*512 + m] = mean * (1.f/16.f);
  #pragma unroll
  for (int hh = 0; hh < 16; ++hh)
    pfb[(((size_t)(b*16 + hh))*512 + l)*512 + m] = acc[hh];
}

// ---------------- top-3 rows per column + pair2node MLP + cond = silu(x + f2n) ----------------
__global__ __launch_bounds__(128) void k_topk_f2n(const float* __restrict__ colm,
      const float* __restrict__ pair, const float* __restrict__ keepf,
      const float* __restrict__ w1, const float* __restrict__ w2,
      const float* __restrict__ xin, float* __restrict__ cond){
  int n = blockIdx.x; int b = n >> 9, m = n & 511;
  __shared__ int sidx[3];
  __shared__ float f2n_s[128];
  __shared__ float u_s[128];
  int tid = threadIdx.x;
  if (tid < 64){
    const float* colbase = colm + ((size_t)b*512)*512 + m;   // [b,l,m] layout, stride 512 over l
    float v[8];
    #pragma unroll
    for (int i = 0; i < 8; ++i) v[i] = colbase[(size_t)(tid + 64*i)*512];
    int c0 = -1, c1 = -1;
    for (int r = 0; r < 3; ++r){
      float bv = -INFINITY; int bi = 1 << 30;
      #pragma unroll
      for (int i = 0; i < 8; ++i){
        int idx = tid + 64*i;
        bool excl = (idx == c0) || (idx == c1);
        float val = v[i];
        if (!excl && (val > bv || (val == bv && idx < bi))){ bv = val; bi = idx; }
      }
      for (int o = 32; o > 0; o >>= 1){     // wave argmax, tie -> lower index
        float ov = __shfl_down(bv, o);
        int   oi = __shfl_down(bi, o);
        if (ov > bv || (ov == bv && oi < bi)){ bv = ov; bi = oi; }
      }
      bi = __shfl(bi, 0);
      if (tid == 0) sidx[r] = bi;
      if (r == 0) c0 = bi; else c1 = bi;
    }
  }
  __syncthreads();
  int i0 = sidx[0], i1 = sidx[1], i2 = sidx[2];
  float kc = keepf[n];
  float k0 = keepf[b*512 + i0], k1 = keepf[b*512 + i1], k2 = keepf[b*512 + i2];
  {
    int p = tid;
    float s = k0*pair[(((size_t)(b*512 + i0))*512 + m)*128 + p]
            + k1*pair[(((size_t)(b*512 + i1))*512 + m)*128 + p]
            + k2*pair[(((size_t)(b*512 + i2))*512 + m)*128 + p];
    f2n_s[p] = s * kc * (1.f/3.f);
  }
  __syncthreads();
  {
    int j = tid;
    const float* wr = w1 + (size_t)j*128;
    float acc = 0.f;
    #pragma unroll 8
    for (int p = 0; p < 128; ++p) acc += f2n_s[p]*wr[p];
    u_s[j] = siluf(acc);
  }
  __syncthreads();
  for (int d = tid; d < 512; d += 128){
    const float* wr = w2 + (size_t)d*128;
    float acc = 0.f;
    #pragma unroll 8
    for (int p = 0; p < 128; ++p) acc += u_s[p]*wr[p];
    float xv = xin[((size_t)(m*2 + b))*512 + d];     // x is [L,B,D]
    cond[(size_t)n*512 + d] = siluf(xv + acc);
  }
}

// ---------------- hin = h + time_emb ----------------
__global__ __launch_bounds__(128) void k_addte(const float* __restrict__ h,
      const float* __restrict__ te, float* __restrict__ hin){
  int n = blockIdx.x; int b = n >> 9;
  int tid = threadIdx.x;
  float4 v = ((const float4*)(h  + (size_t)n*512))[tid];
  float4 t = ((const float4*)(te + (size_t)b*512))[tid];
  v.x += t.x; v.y += t.y; v.z += t.z; v.w += t.w;
  ((float4*)(hin + (size_t)n*512))[tid] = v;
}

// ---------------- LayerNorm + adaLN modulate ----------------
__global__ __launch_bounds__(128) void k_lnmod(const float* __restrict__ hin,
      const float* __restrict__ mod, float* __restrict__ out, int sh_off, int sc_off){
  int n = blockIdx.x;
  int tid = threadIdx.x;
  float4 v = ((const float4*)(hin + (size_t)n*512))[tid];
  float s = v.x + v.y + v.z + v.w;
  float q = v.x*v.x + v.y*v.y + v.z*v.z + v.w*v.w;
  #pragma unroll
  for (int o = 1; o < 64; o <<= 1){ s += __shfl_xor(s, o); q += __shfl_xor(q, o); }
  __shared__ float s2[2], q2[2];
  if ((tid & 63) == 0){ s2[tid >> 6] = s; q2[tid >> 6] = q; }
  __syncthreads();
  float S = s2[0] + s2[1], Q = q2[0] + q2[1];
  float mean = S * (1.f/512.f);
  float var  = Q * (1.f/512.f) - mean*mean;
  float rstd = rsqrtf(var + 1e-5f);
  const float* mrow = mod + (size_t)n*3072;
  float4 sc = *(const float4*)(mrow + sc_off + tid*4);
  float4 sh = *(const float4*)(mrow + sh_off + tid*4);
  float4 rv;
  rv.x = (v.x - mean)*rstd*(1.f + sc.x) + sh.x;
  rv.y = (v.y - mean)*rstd*(1.f + sc.y) + sh.y;
  rv.z = (v.z - mean)*rstd*(1.f + sc.z) + sh.z;
  rv.w = (v.w - mean)*rstd*(1.f + sc.w) + sh.w;
  ((float4*)(out + (size_t)n*512))[tid] = rv;
}

// ---------------- bf16 MFMA GEMM: C[M,N] = epi(A[M,K] @ Bw[N,K]^T + bias) ----------------
// epi: 0 none, 1 res + gate*val, 2 gelu. A,Bw f32 -> bf16 on the fly, f32 accumulate.
__global__ __launch_bounds__(256) void k_gemm_mfma(const float* __restrict__ A,
      const float* __restrict__ Bw, const float* __restrict__ bias,
      float* __restrict__ C, int M, int N, int K, int epi,
      const float* __restrict__ res, const float* __restrict__ gate, int gate_ld){
  __shared__ bf16_t As[64*32];
  __shared__ bf16_t Bs[64*32];
  int tid = threadIdx.x;
  int m0 = blockIdx.y*64, n0 = blockIdx.x*64;
  // staging: thread covers 8 consecutive floats (one 16B bf16 slot)
  int srow = tid >> 2, sslot = tid & 3;
  int saddr = srow*32 + ((sslot ^ (srow & 3)) << 3);   // XOR-swizzled slot
  const float* ap = A  + (size_t)(m0 + srow)*K + (sslot << 3);
  const float* bp = Bw + (size_t)(n0 + srow)*K + (sslot << 3);
  // MFMA fragment addressing
  int lane = tid & 63;
  int wid = tid >> 6;
  int wr = wid >> 1, wc = wid & 1;        // wave -> 32x32 quadrant
  int frow = lane & 15, g = lane >> 4;
  int swz = (g ^ (frow & 3)) << 3;
  int arow0 = wr*32 + frow;
  int brow0 = wc*32 + frow;
  f32x4 acc[2][2] = {};
  for (int k0 = 0; k0 < K; k0 += 32){
    float4 a0 = *(const float4*)(ap + k0);
    float4 a1 = *(const float4*)(ap + k0 + 4);
    float4 b0 = *(const float4*)(bp + k0);
    float4 b1 = *(const float4*)(bp + k0 + 4);
    bf16x8 av, bv;
    av[0]=(bf16_t)a0.x; av[1]=(bf16_t)a0.y; av[2]=(bf16_t)a0.z; av[3]=(bf16_t)a0.w;
    av[4]=(bf16_t)a1.x; av[5]=(bf16_t)a1.y; av[6]=(bf16_t)a1.z; av[7]=(bf16_t)a1.w;
    bv[0]=(bf16_t)b0.x; bv[1]=(bf16_t)b0.y; bv[2]=(bf16_t)b0.z; bv[3]=(bf16_t)b0.w;
    bv[4]=(bf16_t)b1.x; bv[5]=(bf16_t)b1.y; bv[6]=(bf16_t)b1.z; bv[7]=(bf16_t)b1.w;
    __syncthreads();
    *(bf16x8*)&As[saddr] = av;
    *(bf16x8*)&Bs[saddr] = bv;
    __syncthreads();
    bf16x8 af0 = *(const bf16x8*)&As[(arow0     )*32 + swz];
    bf16x8 af1 = *(const bf16x8*)&As[(arow0 + 16)*32 + swz];
    bf16x8 bf0 = *(const bf16x8*)&Bs[(brow0     )*32 + swz];
    bf16x8 bf1 = *(const bf16x8*)&Bs[(brow0 + 16)*32 + swz];
    acc[0][0] = __builtin_amdgcn_mfma_f32_16x16x32_bf16(af0, bf0, acc[0][0], 0,0,0);
    acc[0][1] = __builtin_amdgcn_mfma_f32_16x16x32_bf16(af0, bf1, acc[0][1], 0,0,0);
    acc[1][0] = __builtin_amdgcn_mfma_f32_16x16x32_bf16(af1, bf0, acc[1][0], 0,0,0);
    acc[1][1] = __builtin_amdgcn_mfma_f32_16x16x32_bf16(af1, bf1, acc[1][1], 0,0,0);
  }
  int r4 = (lane >> 4)*4;
  #pragma unroll
  for (int fm = 0; fm < 2; ++fm){
    int row0 = m0 + wr*32 + fm*16 + r4;
    #pragma unroll
    for (int fn = 0; fn < 2; ++fn){
      int col = n0 + wc*32 + fn*16 + frow;
      float bb = bias[col];
      #pragma unroll
      for (int i = 0; i < 4; ++i){
        int row = row0 + i;
        float v = acc[fm][fn][i] + bb;
        if (epi == 1)      v = res[(size_t)row*N + col] + gate[(size_t)row*gate_ld + col]*v;
        else if (epi == 2) v = geluf(v);
        C[(size_t)row*N + col] = v;
      }
    }
  }
}

// ---------------- attention: per (b,h), 16 q-rows per block ----------------
__global__ __launch_bounds__(256) void k_attn(const float* __restrict__ qkv,
      const float* __restrict__ pfb, const float* __restrict__ keepf,
      float* __restrict__ obuf){
  int blk = blockIdx.x;
  int tile = blk & 31;       // L/16 tiles
  int bh = blk >> 5;         // b*16 + h
  int b = bh >> 4;
  int r0 = tile*16;
  int hbase = (bh & 15)*32;
  __shared__ float qs[16][36];
  __shared__ float ks[64][36];
  __shared__ float ss[16][516];
  __shared__ float inv_s[16];
  int tid = threadIdx.x;
  {
    int idx = tid;
    #pragma unroll
    for (int i = 0; i < 2; ++i, idx += 256){
      int r = idx >> 5, dh = idx & 31;
      qs[r][dh] = qkv[((size_t)(b*512 + r0 + r))*1536 + hbase + dh];
    }
  }
  const float scale = 0.17677669529663687f;  // 1/sqrt(32)
  int r = tid >> 4, mo = tid & 15;
  for (int mc = 0; mc < 8; ++mc){
    __syncthreads();
    {
      int idx = tid;
      #pragma unroll
      for (int i = 0; i < 8; ++i, idx += 256){
        int ml = idx >> 5, dh = idx & 31;
        ks[ml][dh] = qkv[((size_t)(b*512 + mc*64 + ml))*1536 + 512 + hbase + dh];
      }
    }
    __syncthreads();
    const float4* qrow = (const float4*)&qs[r][0];
    #pragma unroll
    for (int j = 0; j < 4; ++j){
      int ml = mo + 16*j;
      const float4* krow = (const float4*)&ks[ml][0];
      float acc = 0.f;
      #pragma unroll
      for (int t = 0; t < 8; ++t){
        float4 qa = qrow[t], ka = krow[t];
        acc += qa.x*ka.x + qa.y*ka.y + qa.z*ka.z + qa.w*ka.w;
      }
      int m = mc*64 + ml;
      float sv = acc*scale + pfb[((size_t)bh*512 + (r0 + r))*512 + m];
      if (keepf[b*512 + m] == 0.f) sv = -1e9f;
      ss[r][m] = sv;
    }
  }
  // softmax: row r owned by 16 lanes of one wave -> wave-local
  {
    float mx = -INFINITY;
    for (int t = 0; t < 32; ++t) mx = fmaxf(mx, ss[r][mo + 16*t]);
    #pragma unroll
    for (int o = 1; o < 16; o <<= 1) mx = fmaxf(mx, __shfl_xor(mx, o));
    float sum = 0.f;
    for (int t = 0; t < 32; ++t){
      int m = mo + 16*t;
      float e = expf(ss[r][m] - mx);
      ss[r][m] = e;
      sum += e;
    }
    #pragma unroll
    for (int o = 1; o < 16; o <<= 1) sum += __shfl_xor(sum, o);
    if (mo == 0) inv_s[r] = 1.f/sum;
  }
  // PV
  float acc0 = 0.f, acc1 = 0.f;
  int dho = mo;
  for (int mc = 0; mc < 8; ++mc){
    __syncthreads();
    {
      int idx = tid;
      #pragma unroll
      for (int i = 0; i < 8; ++i, idx += 256){
        int ml = idx >> 5, dh = idx & 31;
        ks[ml][dh] = qkv[((size_t)(b*512 + mc*64 + ml))*1536 + 1024 + hbase + dh];
      }
    }
    __syncthreads();
    #pragma unroll 8
    for (int ml = 0; ml < 64; ++ml){
      float p = ss[r][mc*64 + ml];
      float2 vv = *(const float2*)&ks[ml][dho*2];
      acc0 += p*vv.x; acc1 += p*vv.y;
    }
  }
  float inv = inv_s[r];
  float2 o2; o2.x = acc0*inv; o2.y = acc1*inv;
  *(float2*)(obuf + ((size_t)(b*512 + r0 + r))*512 + hbase + dho*2) = o2;
}

extern "C" void kernel_launch(void* const* d_in, const int* in_sizes, int n_in,
                              void* d_out, int out_size, void* d_ws, size_t ws_size,
                              hipStream_t stream){
  (void)in_sizes; (void)n_in; (void)out_size; (void)ws_size;
  const float* x        = (const float*)d_in[0];
  const float* pos      = (const float*)d_in[1];
  const float* time_emb = (const float*)d_in[2];
  const float* pair     = (const float*)d_in[3];
  const float* pos_w    = (const float*)d_in[4];
  const float* pfb_w    = (const float*)d_in[5];
  const float* p2n_w1   = (const float*)d_in[6];
  const float* p2n_w2   = (const float*)d_in[7];
  const float* adaln_w  = (const float*)d_in[8];
  const float* adaln_b  = (const float*)d_in[9];
  const float* qkv_w    = (const float*)d_in[10];
  const float* qkv_b    = (const float*)d_in[11];
  const float* proj_w   = (const float*)d_in[12];
  const float* proj_b   = (const float*)d_in[13];
  const float* mlp_w1   = (const float*)d_in[14];
  const float* mlp_b1   = (const float*)d_in[15];
  const float* mlp_w2   = (const float*)d_in[16];
  const float* mlp_b2   = (const float*)d_in[17];
  const int*   maskp    = (const int*)d_in[18];

  float* W = (float*)d_ws;
  size_t off = 0;
  auto alloc = [&](size_t nelem){ float* p = W + off; off += nelem; return p; };
  float* h      = alloc((size_t)NT_*D_);
  float* cond   = alloc((size_t)NT_*D_);
  float* keepf  = alloc(NT_);
  float* pfbbuf = alloc((size_t)B_*H_*L_*L_);
  float* colm   = alloc((size_t)B_*L_*L_);
  float* modb   = alloc((size_t)NT_*6*D_);
  float* qkvb   = alloc((size_t)NT_*3*D_);
  float* midb   = alloc((size_t)NT_*FF_);
  float* hin    = alloc((size_t)NT_*D_);
  float* hin2   = alloc((size_t)NT_*D_);
  float* abuf   = alloc((size_t)NT_*D_);
  float* obuf   = alloc((size_t)NT_*D_);

  k_posemb<<<NT_, 256, 0, stream>>>(pos, pos_w, maskp, h, keepf);
  k_pfb2<<<NT_*2, 256, 0, stream>>>(pair, pfb_w, pfbbuf, colm);
  k_topk_f2n<<<NT_, 128, 0, stream>>>(colm, pair, keepf, p2n_w1, p2n_w2, x, cond);

  for (int l = 0; l < NL_; ++l){
    k_addte<<<NT_, 128, 0, stream>>>(h, time_emb, hin);
    k_gemm_mfma<<<dim3(48,16), 256, 0, stream>>>(cond, adaln_w + (size_t)l*6*D_*D_,
        adaln_b + (size_t)l*6*D_, modb, NT_, 6*D_, D_, 0, nullptr, nullptr, 0);
    k_lnmod<<<NT_, 128, 0, stream>>>(hin, modb, abuf, 0, D_);
    k_gemm_mfma<<<dim3(24,16), 256, 0, stream>>>(abuf, qkv_w + (size_t)l*3*D_*D_,
        qkv_b + (size_t)l*3*D_, qkvb, NT_, 3*D_, D_, 0, nullptr, nullptr, 0);
    k_attn<<<B_*H_*(L_/16), 256, 0, stream>>>(qkvb, pfbbuf, keepf, obuf);
    k_gemm_mfma<<<dim3(8,16), 256, 0, stream>>>(obuf, proj_w + (size_t)l*D_*D_,
        proj_b + (size_t)l*D_, hin2, NT_, D_, D_, 1, hin, modb + 2*D_, 6*D_);
    k_lnmod<<<NT_, 128, 0, stream>>>(hin2, modb, abuf, 3*D_, 4*D_);
    k_gemm_mfma<<<dim3(32,16), 256, 0, stream>>>(abuf, mlp_w1 + (size_t)l*FF_*D_,
        mlp_b1 + (size_t)l*FF_, midb, NT_, FF_, D_, 2, nullptr, nullptr, 0);
    float* hout = (l == NL_-1) ? (float*)d_out : h;
    k_gemm_mfma<<<dim3(8,16), 256, 0, stream>>>(midb, mlp_w2 + (size_t)l*D_*FF_,
        mlp_b2 + (size_t)l*D_, hout, NT_, D_, FF_, 1, hin2, modb + 5*D_, 6*D_);
  }
}

// Round 4
// 346.756 us; speedup vs baseline: 3.2519x; 1.8446x over previous
//
#include <hip/hip_runtime.h>
#include <hip/hip_bf16.h>
#include <math.h>

#define B_  2
#define L_  512
#define D_  512
#define H_  16
#define P_  128
#define NL_ 2
#define DH_ 32
#define FF_ 2048
#define NT_ (B_*L_)

typedef __bf16 bf16_t;
typedef bf16_t bf16x8 __attribute__((ext_vector_type(8)));
typedef bf16_t bf16x4 __attribute__((ext_vector_type(4)));
typedef bf16_t bf16x2 __attribute__((ext_vector_type(2)));
typedef float  f32x4  __attribute__((ext_vector_type(4)));

__device__ __forceinline__ float siluf(float x){ return x / (1.f + __expf(-x)); }
__device__ __forceinline__ float geluf(float x){
  const float c = 0.7978845608028654f;  // sqrt(2/pi)
  float x3 = x*x*x;
  return 0.5f*x*(1.f + tanhf(c*(x + 0.044715f*x3)));
}

__device__ __forceinline__ void gload16(const bf16_t* g, bf16_t* l){
  __builtin_amdgcn_global_load_lds(
      (const __attribute__((address_space(1))) unsigned int*)g,
      (__attribute__((address_space(3))) unsigned int*)l, 16, 0, 0);
}

// ---------------- weight f32 -> bf16 conversion (all 5 weight blobs) ----------------
__global__ __launch_bounds__(256) void k_cvtw(const float* __restrict__ s0,
      const float* __restrict__ s1, const float* __restrict__ s2,
      const float* __restrict__ s3, const float* __restrict__ s4,
      bf16_t* __restrict__ dst){
  const size_t c0=3145728, c1=4718592, c2=5242880, c3=7340032, c4=9437184;
  size_t e = ((size_t)blockIdx.x*256 + threadIdx.x)*4;
  if (e >= c4) return;
  const float* s; size_t off;
  if      (e < c0){ s=s0; off=e; }
  else if (e < c1){ s=s1; off=e-c0; }
  else if (e < c2){ s=s2; off=e-c1; }
  else if (e < c3){ s=s3; off=e-c2; }
  else            { s=s4; off=e-c3; }
  float4 v = *(const float4*)(s + off);
  bf16x4 o; o[0]=(bf16_t)v.x; o[1]=(bf16_t)v.y; o[2]=(bf16_t)v.z; o[3]=(bf16_t)v.w;
  *(bf16x4*)(dst + e) = o;
}

// ---------------- pos embedding + keep mask ----------------
__global__ __launch_bounds__(256) void k_posemb(const float* __restrict__ pos,
      const float* __restrict__ w, const int* __restrict__ maskp,
      float* __restrict__ h, float* __restrict__ keepf){
  int n = blockIdx.x;                       // b*L + l
  float kf = (maskp[n] != 0) ? 0.f : 1.f;   // True = pad
  if (threadIdx.x == 0) keepf[n] = kf;
  float p0 = pos[n*3+0], p1 = pos[n*3+1], p2 = pos[n*3+2];
  for (int d = threadIdx.x; d < D_; d += 256){
    float v = p0*w[d*3+0] + p1*w[d*3+1] + p2*w[d*3+2];
    h[(size_t)n*D_ + d] = kf*v;
  }
}

// ---------------- pair bias fused with col-mean ----------------
__global__ __launch_bounds__(256) void k_pfb2(const float* __restrict__ pair,
      const float* __restrict__ w, bf16_t* __restrict__ pfb, float* __restrict__ colm){
  int blk = blockIdx.x;
  int mc = blk & 1;            // m half (256 each)
  int n  = blk >> 1;           // b*L + l
  int b = n >> 9, l = n & 511;
  int tid = threadIdx.x;
  __shared__ float sw[16][128];
  {
    float4* swv = (float4*)&sw[0][0];
    const float4* wv = (const float4*)w;
    swv[tid] = wv[tid];
    swv[tid + 256] = wv[tid + 256];
  }
  __syncthreads();
  int m = mc*256 + tid;
  const float* rowp = pair + (((size_t)n)*512 + m)*128;
  float acc[16] = {};
  #pragma unroll 4
  for (int pc = 0; pc < 32; ++pc){
    float4 v = ((const float4*)rowp)[pc];
    v.x = siluf(v.x); v.y = siluf(v.y); v.z = siluf(v.z); v.w = siluf(v.w);
    #pragma unroll
    for (int hh = 0; hh < 16; ++hh){
      float4 wv = *(const float4*)&sw[hh][pc*4];   // wave-uniform broadcast
      acc[hh] += v.x*wv.x + v.y*wv.y + v.z*wv.z + v.w*wv.w;
    }
  }
  float mean = 0.f;
  #pragma unroll
  for (int hh = 0; hh < 16; ++hh) mean += acc[hh];
  colm[((size_t)n)*512 + m] = mean * (1.f/16.f);
  #pragma unroll
  for (int hh = 0; hh < 16; ++hh)
    pfb[(((size_t)(b*16 + hh))*512 + l)*512 + m] = (bf16_t)acc[hh];
}

// ---------------- top-3 rows per column + pair2node MLP + cond = silu(x + f2n) ----------------
__global__ __launch_bounds__(128) void k_topk_f2n(const float* __restrict__ colm,
      const float* __restrict__ pair, const float* __restrict__ keepf,
      const float* __restrict__ w1, const float* __restrict__ w2,
      const float* __restrict__ xin, bf16_t* __restrict__ cond){
  int n = blockIdx.x; int b = n >> 9, m = n & 511;
  __shared__ int sidx[3];
  __shared__ float f2n_s[128];
  __shared__ float u_s[128];
  int tid = threadIdx.x;
  if (tid < 64){
    const float* colbase = colm + ((size_t)b*512)*512 + m;   // stride 512 over l
    float v[8];
    #pragma unroll
    for (int i = 0; i < 8; ++i) v[i] = colbase[(size_t)(tid + 64*i)*512];
    int c0 = -1, c1 = -1;
    for (int r = 0; r < 3; ++r){
      float bv = -INFINITY; int bi = 1 << 30;
      #pragma unroll
      for (int i = 0; i < 8; ++i){
        int idx = tid + 64*i;
        bool excl = (idx == c0) || (idx == c1);
        float val = v[i];
        if (!excl && (val > bv || (val == bv && idx < bi))){ bv = val; bi = idx; }
      }
      for (int o = 32; o > 0; o >>= 1){
        float ov = __shfl_down(bv, o);
        int   oi = __shfl_down(bi, o);
        if (ov > bv || (ov == bv && oi < bi)){ bv = ov; bi = oi; }
      }
      bi = __shfl(bi, 0);
      if (tid == 0) sidx[r] = bi;
      if (r == 0) c0 = bi; else c1 = bi;
    }
  }
  __syncthreads();
  int i0 = sidx[0], i1 = sidx[1], i2 = sidx[2];
  float kc = keepf[n];
  float k0 = keepf[b*512 + i0], k1 = keepf[b*512 + i1], k2 = keepf[b*512 + i2];
  {
    int p = tid;
    float s = k0*pair[(((size_t)(b*512 + i0))*512 + m)*128 + p]
            + k1*pair[(((size_t)(b*512 + i1))*512 + m)*128 + p]
            + k2*pair[(((size_t)(b*512 + i2))*512 + m)*128 + p];
    f2n_s[p] = s * kc * (1.f/3.f);
  }
  __syncthreads();
  {
    int j = tid;
    const float* wr = w1 + (size_t)j*128;
    float acc = 0.f;
    #pragma unroll 8
    for (int p = 0; p < 128; ++p) acc += f2n_s[p]*wr[p];
    u_s[j] = siluf(acc);
  }
  __syncthreads();
  for (int d = tid; d < 512; d += 128){
    const float* wr = w2 + (size_t)d*128;
    float acc = 0.f;
    #pragma unroll 8
    for (int p = 0; p < 128; ++p) acc += u_s[p]*wr[p];
    float xv = xin[((size_t)(m*2 + b))*512 + d];     // x is [L,B,D]
    cond[(size_t)n*512 + d] = (bf16_t)siluf(xv + acc);
  }
}

// ---------------- LayerNorm(h [+ te]) * (1+sc) + sh -> bf16 ----------------
__global__ __launch_bounds__(128) void k_lnmod2(const float* __restrict__ hbase,
      const float* __restrict__ te, const float* __restrict__ mod,
      bf16_t* __restrict__ out, int sh_off, int sc_off){
  int n = blockIdx.x; int b = n >> 9;
  int tid = threadIdx.x;
  float4 v = ((const float4*)(hbase + (size_t)n*512))[tid];
  if (te){
    float4 t = ((const float4*)(te + (size_t)b*512))[tid];
    v.x += t.x; v.y += t.y; v.z += t.z; v.w += t.w;
  }
  float s = v.x + v.y + v.z + v.w;
  float q = v.x*v.x + v.y*v.y + v.z*v.z + v.w*v.w;
  #pragma unroll
  for (int o = 1; o < 64; o <<= 1){ s += __shfl_xor(s, o); q += __shfl_xor(q, o); }
  __shared__ float s2[2], q2[2];
  if ((tid & 63) == 0){ s2[tid >> 6] = s; q2[tid >> 6] = q; }
  __syncthreads();
  float S = s2[0] + s2[1], Q = q2[0] + q2[1];
  float mean = S * (1.f/512.f);
  float var  = Q * (1.f/512.f) - mean*mean;
  float rstd = rsqrtf(var + 1e-5f);
  const float* mrow = mod + (size_t)n*3072;
  float4 sc = *(const float4*)(mrow + sc_off + tid*4);
  float4 sh = *(const float4*)(mrow + sh_off + tid*4);
  bf16x4 rv;
  rv[0] = (bf16_t)((v.x - mean)*rstd*(1.f + sc.x) + sh.x);
  rv[1] = (bf16_t)((v.y - mean)*rstd*(1.f + sc.y) + sh.y);
  rv[2] = (bf16_t)((v.z - mean)*rstd*(1.f + sc.z) + sh.z);
  rv[3] = (bf16_t)((v.w - mean)*rstd*(1.f + sc.w) + sh.w);
  *(bf16x4*)(out + (size_t)n*512 + tid*4) = rv;
}

// ---------------- bf16 MFMA GEMM with global_load_lds staging ----------------
// C[M,N] = epi(A[M,K] @ Bw[N,K]^T + bias)
// epi: 0 plain f32 | 1 proj: outf = res + te + gate*v | 2 gelu->bf16
//      3 qkv->bf16 (+vT for V cols) | 4 mlp2: outf = res + gate*v
template<bool SMALL>
__global__ __launch_bounds__(256) void k_gemm_bf(const bf16_t* __restrict__ A,
      const bf16_t* __restrict__ Bw, const float* __restrict__ bias,
      int M, int N, int K, int epi,
      float* __restrict__ outf, bf16_t* __restrict__ outb,
      const float* __restrict__ res, const float* __restrict__ gate,
      const float* __restrict__ te, bf16_t* __restrict__ vT){
  const int BN = SMALL ? 32 : 64;
  __shared__ __align__(16) bf16_t As[64*64];
  __shared__ __align__(16) bf16_t Bs[(SMALL?32:64)*64];
  int tid = threadIdx.x;
  int m0 = blockIdx.y*64, n0 = blockIdx.x*BN;
  int lane = tid & 63, wid = tid >> 6;
  int wr = SMALL ? wid : (wid>>1);
  int wc = SMALL ? 0 : (wid&1);
  const int FM = SMALL ? 1 : 2;
  const int WMR = SMALL ? 16 : 32;
  int frow = lane & 15, g = lane >> 4;
  f32x4 acc[2][2] = {};
  for (int k0 = 0; k0 < K; k0 += 64){
    {
      int e = tid;
      #pragma unroll
      for (int i = 0; i < 2; ++i, e += 256){     // A: 64x64 bf16 = 512 x 16B
        int row = e >> 3, cb = e & 7;
        gload16(A + (size_t)(m0+row)*K + k0 + ((cb ^ (row&7))<<3), As + e*8);
      }
      e = tid;
      #pragma unroll
      for (int i = 0; i < (SMALL?1:2); ++i, e += 256){
        int row = e >> 3, cb = e & 7;
        gload16(Bw + (size_t)(n0+row)*K + k0 + ((cb ^ (row&7))<<3), Bs + e*8);
      }
    }
    __syncthreads();                              // drains vmcnt -> staged
    #pragma unroll
    for (int ks = 0; ks < 2; ++ks){
      bf16x8 af[2], bfv[2];
      #pragma unroll
      for (int fm = 0; fm < FM; ++fm){
        int ar = wr*WMR + fm*16 + frow;
        af[fm] = *(const bf16x8*)&As[ar*64 + (((ks*4+g) ^ (ar&7))<<3)];
      }
      #pragma unroll
      for (int fn = 0; fn < 2; ++fn){
        int br = wc*32 + fn*16 + frow;
        bfv[fn] = *(const bf16x8*)&Bs[br*64 + (((ks*4+g) ^ (br&7))<<3)];
      }
      #pragma unroll
      for (int fm = 0; fm < FM; ++fm)
        #pragma unroll
        for (int fn = 0; fn < 2; ++fn)
          acc[fm][fn] = __builtin_amdgcn_mfma_f32_16x16x32_bf16(af[fm], bfv[fn], acc[fm][fn], 0,0,0);
    }
    __syncthreads();
  }
  #pragma unroll
  for (int fm = 0; fm < FM; ++fm){
    #pragma unroll
    for (int fn = 0; fn < 2; ++fn){
      int n = n0 + wc*32 + fn*16 + frow;
      float bb = bias[n];
      int row0 = m0 + wr*WMR + fm*16 + g*4;
      if (epi == 3 && n >= 1024){
        int hh = (n-1024)>>5, dh = (n-1024)&31;
        int b = row0>>9, ll = row0&511;
        bf16x4 pv;
        #pragma unroll
        for (int i = 0; i < 4; ++i){
          float v = acc[fm][fn][i] + bb;
          outb[(size_t)(row0+i)*N + n] = (bf16_t)v;
          pv[i] = (bf16_t)v;
        }
        *(bf16x4*)&vT[(((size_t)(b*16+hh))*32 + dh)*512 + ll] = pv;
      } else {
        #pragma unroll
        for (int i = 0; i < 4; ++i){
          int row = row0 + i;
          float v = acc[fm][fn][i] + bb;
          if (epi == 1){
            v = res[(size_t)row*N + n] + te[(row>>9)*D_ + n] + gate[(size_t)row*(6*D_) + n]*v;
            outf[(size_t)row*N + n] = v;
          } else if (epi == 2){
            outb[(size_t)row*N + n] = (bf16_t)geluf(v);
          } else if (epi == 3){
            outb[(size_t)row*N + n] = (bf16_t)v;
          } else if (epi == 4){
            v = res[(size_t)row*N + n] + gate[(size_t)row*(6*D_) + n]*v;
            outf[(size_t)row*N + n] = v;
          } else {
            outf[(size_t)row*N + n] = v;
          }
        }
      }
    }
  }
}

// ---------------- MFMA attention: block = (b,h,16-row q-tile) ----------------
__global__ __launch_bounds__(256) void k_attn2(const bf16_t* __restrict__ qkv,
      const bf16_t* __restrict__ vT, const bf16_t* __restrict__ pfb,
      const float* __restrict__ keepf, bf16_t* __restrict__ obuf){
  __shared__ float ss[16][516];
  __shared__ float opart[4][16][33];
  __shared__ float inv_s[16];
  int blk = blockIdx.x;
  int qt = blk & 31;
  int bh = blk >> 5;
  int b = bh >> 4, h = bh & 15;
  int r0 = qt*16;
  int tid = threadIdx.x;
  int lane = tid & 63, w = tid >> 6;
  int frow = lane & 15, g = lane >> 4;
  const float scale = 0.17677669529663687f;  // 1/sqrt(32)
  bf16x8 qf = *(const bf16x8*)(qkv + (size_t)(b*512 + r0 + frow)*1536 + h*32 + g*8);
  // phase 1: S = QK^T*scale + pfb, masked; wave w covers k in [w*128, w*128+128)
  for (int t = 0; t < 8; ++t){
    int kc = w*128 + t*16;
    bf16x8 kf = *(const bf16x8*)(qkv + (size_t)(b*512 + kc + frow)*1536 + 512 + h*32 + g*8);
    f32x4 s4 = {};
    s4 = __builtin_amdgcn_mfma_f32_16x16x32_bf16(qf, kf, s4, 0,0,0);
    int tok = kc + frow;
    float kp = keepf[b*512 + tok];
    const bf16_t* pf = pfb + ((size_t)bh*512 + r0 + g*4)*512 + tok;
    #pragma unroll
    for (int i = 0; i < 4; ++i){
      float sv = s4[i]*scale + (float)pf[(size_t)i*512];
      sv = (kp == 0.f) ? -1e9f : sv;
      ss[g*4+i][tok] = sv;
    }
  }
  __syncthreads();
  // softmax (unnormalized e kept in ss; inv_s per row)
  {
    int r = tid >> 4, mo = tid & 15;
    float mx = -INFINITY;
    #pragma unroll 8
    for (int t2 = 0; t2 < 32; ++t2) mx = fmaxf(mx, ss[r][mo + 16*t2]);
    #pragma unroll
    for (int o = 1; o < 16; o <<= 1) mx = fmaxf(mx, __shfl_xor(mx, o));
    float sum = 0.f;
    #pragma unroll 8
    for (int t2 = 0; t2 < 32; ++t2){
      int m = mo + 16*t2;
      float e = __expf(ss[r][m] - mx);
      ss[r][m] = e;
      sum += e;
    }
    #pragma unroll
    for (int o = 1; o < 16; o <<= 1) sum += __shfl_xor(sum, o);
    if (mo == 0) inv_s[r] = 1.f/sum;
  }
  __syncthreads();
  // phase 2: O_partial = P[16, w-range] @ V[w-range, 32]
  f32x4 oacc[2] = {};
  for (int t = 0; t < 4; ++t){
    int kc = w*128 + t*32;
    float4 p0 = *(const float4*)&ss[frow][kc + g*8];
    float4 p1 = *(const float4*)&ss[frow][kc + g*8 + 4];
    bf16x8 pfr;
    pfr[0]=(bf16_t)p0.x; pfr[1]=(bf16_t)p0.y; pfr[2]=(bf16_t)p0.z; pfr[3]=(bf16_t)p0.w;
    pfr[4]=(bf16_t)p1.x; pfr[5]=(bf16_t)p1.y; pfr[6]=(bf16_t)p1.z; pfr[7]=(bf16_t)p1.w;
    #pragma unroll
    for (int fn = 0; fn < 2; ++fn){
      bf16x8 vf = *(const bf16x8*)(vT + ((size_t)bh*32 + fn*16 + frow)*512 + kc + g*8);
      oacc[fn] = __builtin_amdgcn_mfma_f32_16x16x32_bf16(pfr, vf, oacc[fn], 0,0,0);
    }
  }
  #pragma unroll
  for (int fn = 0; fn < 2; ++fn)
    #pragma unroll
    for (int i = 0; i < 4; ++i)
      opart[w][g*4+i][fn*16+frow] = oacc[fn][i];
  __syncthreads();
  // reduce over waves + normalize + write bf16
  {
    int q = tid >> 4, dh = (tid & 15)*2;
    float o0 = 0.f, o1 = 0.f;
    #pragma unroll
    for (int ww = 0; ww < 4; ++ww){ o0 += opart[ww][q][dh]; o1 += opart[ww][q][dh+1]; }
    float inv = inv_s[q];
    bf16x2 ov; ov[0] = (bf16_t)(o0*inv); ov[1] = (bf16_t)(o1*inv);
    *(bf16x2*)(obuf + (size_t)(b*512 + r0 + q)*512 + h*32 + dh) = ov;
  }
}

extern "C" void kernel_launch(void* const* d_in, const int* in_sizes, int n_in,
                              void* d_out, int out_size, void* d_ws, size_t ws_size,
                              hipStream_t stream){
  (void)in_sizes; (void)n_in; (void)out_size; (void)ws_size;
  const float* x        = (const float*)d_in[0];
  const float* pos      = (const float*)d_in[1];
  const float* time_emb = (const float*)d_in[2];
  const float* pair     = (const float*)d_in[3];
  const float* pos_w    = (const float*)d_in[4];
  const float* pfb_w    = (const float*)d_in[5];
  const float* p2n_w1   = (const float*)d_in[6];
  const float* p2n_w2   = (const float*)d_in[7];
  const float* adaln_w  = (const float*)d_in[8];
  const float* adaln_b  = (const float*)d_in[9];
  const float* qkv_w    = (const float*)d_in[10];
  const float* qkv_b    = (const float*)d_in[11];
  const float* proj_w   = (const float*)d_in[12];
  const float* proj_b   = (const float*)d_in[13];
  const float* mlp_w1   = (const float*)d_in[14];
  const float* mlp_b1   = (const float*)d_in[15];
  const float* mlp_w2   = (const float*)d_in[16];
  const float* mlp_b2   = (const float*)d_in[17];
  const int*   maskp    = (const int*)d_in[18];

  float* W = (float*)d_ws;
  size_t off = 0;
  auto alloc = [&](size_t nfw){ float* p = W + off; off += nfw; return p; };
  float*  h     = alloc(524288);
  float*  hin2  = alloc(524288);
  float*  modb  = alloc(3145728);
  float*  colm  = alloc(524288);
  float*  keepf = alloc(1024);
  bf16_t* pfbb  = (bf16_t*)alloc(4194304);   // 8,388,608 bf16
  bf16_t* condb = (bf16_t*)alloc(262144);    // 524,288 bf16
  bf16_t* abuf  = (bf16_t*)alloc(262144);    // 524,288 bf16
  bf16_t* qkvb  = (bf16_t*)alloc(786432);    // 1,572,864 bf16
  bf16_t* vTb   = (bf16_t*)alloc(262144);    // 524,288 bf16
  bf16_t* midb  = (bf16_t*)alloc(1048576);   // 2,097,152 bf16
  bf16_t* obuf  = (bf16_t*)alloc(262144);    // 524,288 bf16
  bf16_t* wB    = (bf16_t*)alloc(4718592);   // 9,437,184 bf16
  bf16_t* wA  = wB;
  bf16_t* wQ  = wB + 3145728;
  bf16_t* wP  = wB + 4718592;
  bf16_t* wM1 = wB + 5242880;
  bf16_t* wM2 = wB + 7340032;

  k_cvtw<<<9216, 256, 0, stream>>>(adaln_w, qkv_w, proj_w, mlp_w1, mlp_w2, wB);
  k_posemb<<<NT_, 256, 0, stream>>>(pos, pos_w, maskp, h, keepf);
  k_pfb2<<<NT_*2, 256, 0, stream>>>(pair, pfb_w, pfbb, colm);
  k_topk_f2n<<<NT_, 128, 0, stream>>>(colm, pair, keepf, p2n_w1, p2n_w2, x, condb);

  for (int l = 0; l < NL_; ++l){
    // adaLN modulation: modb = cond @ adaln_w^T + b   [1024,3072] f32
    k_gemm_bf<false><<<dim3(48,16), 256, 0, stream>>>(condb, wA + (size_t)l*3072*512,
        adaln_b + (size_t)l*3072, NT_, 3072, 512, 0, modb, nullptr, nullptr, nullptr, nullptr, nullptr);
    // a = LN(h+te)*(1+sc_a)+sh_a -> bf16
    k_lnmod2<<<NT_, 128, 0, stream>>>(h, time_emb, modb, abuf, 0, D_);
    // qkv -> bf16 (+ vT)
    k_gemm_bf<false><<<dim3(24,16), 256, 0, stream>>>(abuf, wQ + (size_t)l*1536*512,
        qkv_b + (size_t)l*1536, NT_, 1536, 512, 3, nullptr, qkvb, nullptr, nullptr, nullptr, vTb);
    k_attn2<<<B_*H_*32, 256, 0, stream>>>(qkvb, vTb, pfbb, keepf, obuf);
    // hin2 = (h+te) + g_a * (o@proj^T + b)
    k_gemm_bf<true><<<dim3(16,16), 256, 0, stream>>>(obuf, wP + (size_t)l*512*512,
        proj_b + (size_t)l*512, NT_, 512, 512, 1, hin2, nullptr, h, modb + 2*D_, time_emb, nullptr);
    k_lnmod2<<<NT_, 128, 0, stream>>>(hin2, nullptr, modb, abuf, 3*D_, 4*D_);
    // mlp1 gelu -> bf16
    k_gemm_bf<false><<<dim3(32,16), 256, 0, stream>>>(abuf, wM1 + (size_t)l*2048*512,
        mlp_b1 + (size_t)l*2048, NT_, 2048, 512, 2, nullptr, midb, nullptr, nullptr, nullptr, nullptr);
    // h_out = hin2 + g_m * (mid@mlp2^T + b)
    float* hout = (l == NL_-1) ? (float*)d_out : h;
    k_gemm_bf<true><<<dim3(16,16), 256, 0, stream>>>(midb, wM2 + (size_t)l*512*2048,
        mlp_b2 + (size_t)l*512, NT_, 512, 2048, 4, hout, nullptr, hin2, modb + 5*D_, nullptr, nullptr);
  }
}

// Round 5
// 332.686 us; speedup vs baseline: 3.3894x; 1.0423x over previous
//
#include <hip/hip_runtime.h>
#include <hip/hip_bf16.h>
#include <math.h>

#define B_  2
#define L_  512
#define D_  512
#define H_  16
#define P_  128
#define NL_ 2
#define DH_ 32
#define FF_ 2048
#define NT_ (B_*L_)

typedef __bf16 bf16_t;
typedef bf16_t bf16x8 __attribute__((ext_vector_type(8)));
typedef bf16_t bf16x4 __attribute__((ext_vector_type(4)));
typedef bf16_t bf16x2 __attribute__((ext_vector_type(2)));
typedef float  f32x4  __attribute__((ext_vector_type(4)));

__device__ __forceinline__ float siluf(float x){ return x / (1.f + __expf(-x)); }
__device__ __forceinline__ float geluf(float x){
  const float c = 0.7978845608028654f;  // sqrt(2/pi)
  float x3 = x*x*x;
  return 0.5f*x*(1.f + tanhf(c*(x + 0.044715f*x3)));
}

__device__ __forceinline__ void gload16(const bf16_t* g, bf16_t* l){
  __builtin_amdgcn_global_load_lds(
      (const __attribute__((address_space(1))) unsigned int*)g,
      (__attribute__((address_space(3))) unsigned int*)l, 16, 0, 0);
}

// ---------------- merged preamble: cvtw (9216 blocks) | posemb (1024) | pfb2 (2048) ----------------
#define NB_CVT 9216
#define NB_POS 1024
__global__ __launch_bounds__(256) void k_pre(
      const float* __restrict__ s0, const float* __restrict__ s1,
      const float* __restrict__ s2, const float* __restrict__ s3,
      const float* __restrict__ s4, bf16_t* __restrict__ wdst,
      const float* __restrict__ pos, const float* __restrict__ posw,
      const int* __restrict__ maskp, float* __restrict__ h, float* __restrict__ keepf,
      const float* __restrict__ pair, const float* __restrict__ pfw,
      bf16_t* __restrict__ pfb, float* __restrict__ colm){
  __shared__ float sw[16][128];
  int bid = blockIdx.x;
  int tid = threadIdx.x;
  if (bid < NB_CVT){
    // weight f32 -> bf16 (5 blobs, boundaries multiple of 1024 -> block-uniform)
    const size_t c0=3145728, c1=4718592, c2=5242880, c3=7340032, c4=9437184;
    size_t e = ((size_t)bid*256 + tid)*4;
    if (e >= c4) return;
    const float* s; size_t off;
    if      (e < c0){ s=s0; off=e; }
    else if (e < c1){ s=s1; off=e-c0; }
    else if (e < c2){ s=s2; off=e-c1; }
    else if (e < c3){ s=s3; off=e-c2; }
    else            { s=s4; off=e-c3; }
    float4 v = *(const float4*)(s + off);
    bf16x4 o; o[0]=(bf16_t)v.x; o[1]=(bf16_t)v.y; o[2]=(bf16_t)v.z; o[3]=(bf16_t)v.w;
    *(bf16x4*)(wdst + e) = o;
    return;
  }
  if (bid < NB_CVT + NB_POS){
    int n = bid - NB_CVT;                     // b*L + l
    float kf = (maskp[n] != 0) ? 0.f : 1.f;   // True = pad
    if (tid == 0) keepf[n] = kf;
    float p0 = pos[n*3+0], p1 = pos[n*3+1], p2 = pos[n*3+2];
    for (int d = tid; d < D_; d += 256){
      float v = p0*posw[d*3+0] + p1*posw[d*3+1] + p2*posw[d*3+2];
      h[(size_t)n*D_ + d] = kf*v;
    }
    return;
  }
  // pair bias fused with col-mean
  int blk = bid - NB_CVT - NB_POS;
  int mc = blk & 1;            // m half (256 each)
  int n  = blk >> 1;           // b*L + l
  int b = n >> 9, l = n & 511;
  {
    float4* swv = (float4*)&sw[0][0];
    const float4* wv = (const float4*)pfw;
    swv[tid] = wv[tid];
    swv[tid + 256] = wv[tid + 256];
  }
  __syncthreads();
  int m = mc*256 + tid;
  const float* rowp = pair + (((size_t)n)*512 + m)*128;
  float acc[16] = {};
  #pragma unroll 4
  for (int pc = 0; pc < 32; ++pc){
    float4 v = ((const float4*)rowp)[pc];
    v.x = siluf(v.x); v.y = siluf(v.y); v.z = siluf(v.z); v.w = siluf(v.w);
    #pragma unroll
    for (int hh = 0; hh < 16; ++hh){
      float4 wv = *(const float4*)&sw[hh][pc*4];   // wave-uniform broadcast
      acc[hh] += v.x*wv.x + v.y*wv.y + v.z*wv.z + v.w*wv.w;
    }
  }
  float mean = 0.f;
  #pragma unroll
  for (int hh = 0; hh < 16; ++hh) mean += acc[hh];
  colm[((size_t)n)*512 + m] = mean * (1.f/16.f);
  #pragma unroll
  for (int hh = 0; hh < 16; ++hh)
    pfb[(((size_t)(b*16 + hh))*512 + l)*512 + m] = (bf16_t)acc[hh];
}

// ---------------- top-3 rows per column + pair2node MLP + cond = silu(x + f2n) ----------------
__global__ __launch_bounds__(128) void k_topk_f2n(const float* __restrict__ colm,
      const float* __restrict__ pair, const float* __restrict__ keepf,
      const float* __restrict__ w1, const float* __restrict__ w2,
      const float* __restrict__ xin, bf16_t* __restrict__ cond){
  int n = blockIdx.x; int b = n >> 9, m = n & 511;
  __shared__ int sidx[3];
  __shared__ float f2n_s[128];
  __shared__ float u_s[128];
  int tid = threadIdx.x;
  if (tid < 64){
    const float* colbase = colm + ((size_t)b*512)*512 + m;   // stride 512 over l
    float v[8];
    #pragma unroll
    for (int i = 0; i < 8; ++i) v[i] = colbase[(size_t)(tid + 64*i)*512];
    int c0 = -1, c1 = -1;
    for (int r = 0; r < 3; ++r){
      float bv = -INFINITY; int bi = 1 << 30;
      #pragma unroll
      for (int i = 0; i < 8; ++i){
        int idx = tid + 64*i;
        bool excl = (idx == c0) || (idx == c1);
        float val = v[i];
        if (!excl && (val > bv || (val == bv && idx < bi))){ bv = val; bi = idx; }
      }
      for (int o = 32; o > 0; o >>= 1){
        float ov = __shfl_down(bv, o);
        int   oi = __shfl_down(bi, o);
        if (ov > bv || (ov == bv && oi < bi)){ bv = ov; bi = oi; }
      }
      bi = __shfl(bi, 0);
      if (tid == 0) sidx[r] = bi;
      if (r == 0) c0 = bi; else c1 = bi;
    }
  }
  __syncthreads();
  int i0 = sidx[0], i1 = sidx[1], i2 = sidx[2];
  float kc = keepf[n];
  float k0 = keepf[b*512 + i0], k1 = keepf[b*512 + i1], k2 = keepf[b*512 + i2];
  {
    int p = tid;
    float s = k0*pair[(((size_t)(b*512 + i0))*512 + m)*128 + p]
            + k1*pair[(((size_t)(b*512 + i1))*512 + m)*128 + p]
            + k2*pair[(((size_t)(b*512 + i2))*512 + m)*128 + p];
    f2n_s[p] = s * kc * (1.f/3.f);
  }
  __syncthreads();
  {
    int j = tid;
    const float* wr = w1 + (size_t)j*128;
    float acc = 0.f;
    #pragma unroll 8
    for (int p = 0; p < 128; ++p) acc += f2n_s[p]*wr[p];
    u_s[j] = siluf(acc);
  }
  __syncthreads();
  for (int d = tid; d < 512; d += 128){
    const float* wr = w2 + (size_t)d*128;
    float acc = 0.f;
    #pragma unroll 8
    for (int p = 0; p < 128; ++p) acc += u_s[p]*wr[p];
    float xv = xin[((size_t)(m*2 + b))*512 + d];     // x is [L,B,D]
    cond[(size_t)n*512 + d] = (bf16_t)siluf(xv + acc);
  }
}

// ---------------- LayerNorm(h [+ te]) * (1+sc) + sh -> bf16 ----------------
__global__ __launch_bounds__(128) void k_lnmod2(const float* __restrict__ hbase,
      const float* __restrict__ te, const float* __restrict__ mod,
      bf16_t* __restrict__ out, int sh_off, int sc_off, int mstride){
  int n = blockIdx.x; int b = n >> 9;
  int tid = threadIdx.x;
  float4 v = ((const float4*)(hbase + (size_t)n*512))[tid];
  if (te){
    float4 t = ((const float4*)(te + (size_t)b*512))[tid];
    v.x += t.x; v.y += t.y; v.z += t.z; v.w += t.w;
  }
  float s = v.x + v.y + v.z + v.w;
  float q = v.x*v.x + v.y*v.y + v.z*v.z + v.w*v.w;
  #pragma unroll
  for (int o = 1; o < 64; o <<= 1){ s += __shfl_xor(s, o); q += __shfl_xor(q, o); }
  __shared__ float s2[2], q2[2];
  if ((tid & 63) == 0){ s2[tid >> 6] = s; q2[tid >> 6] = q; }
  __syncthreads();
  float S = s2[0] + s2[1], Q = q2[0] + q2[1];
  float mean = S * (1.f/512.f);
  float var  = Q * (1.f/512.f) - mean*mean;
  float rstd = rsqrtf(var + 1e-5f);
  const float* mrow = mod + (size_t)n*mstride;
  float4 sc = *(const float4*)(mrow + sc_off + tid*4);
  float4 sh = *(const float4*)(mrow + sh_off + tid*4);
  bf16x4 rv;
  rv[0] = (bf16_t)((v.x - mean)*rstd*(1.f + sc.x) + sh.x);
  rv[1] = (bf16_t)((v.y - mean)*rstd*(1.f + sc.y) + sh.y);
  rv[2] = (bf16_t)((v.z - mean)*rstd*(1.f + sc.z) + sh.z);
  rv[3] = (bf16_t)((v.w - mean)*rstd*(1.f + sc.w) + sh.w);
  *(bf16x4*)(out + (size_t)n*512 + tid*4) = rv;
}

// ---------------- bf16 MFMA GEMM, double-buffered global_load_lds staging ----------------
// C[M,N] = epi(A[M,K] @ Bw[N,K]^T + bias)
// epi: 0 plain f32 | 1 proj: outf = res + te + gate*v | 2 gelu->bf16
//      3 qkv->bf16 (+vT for V cols) | 4 mlp2: outf = res + gate*v
template<bool SMALL>
__global__ __launch_bounds__(256) void k_gemm_bf(const bf16_t* __restrict__ A,
      const bf16_t* __restrict__ Bw, const float* __restrict__ bias,
      int M, int N, int K, int epi,
      float* __restrict__ outf, bf16_t* __restrict__ outb,
      const float* __restrict__ res, const float* __restrict__ gate, int gate_ld,
      const float* __restrict__ te, bf16_t* __restrict__ vT){
  const int BN = SMALL ? 32 : 64;
  __shared__ __align__(16) bf16_t As[2][64*64];
  __shared__ __align__(16) bf16_t Bs[2][(SMALL?32:64)*64];
  int tid = threadIdx.x;
  int m0 = blockIdx.y*64, n0 = blockIdx.x*BN;
  int lane = tid & 63, wid = tid >> 6;
  int wr = SMALL ? wid : (wid>>1);
  int wc = SMALL ? 0 : (wid&1);
  const int FM = SMALL ? 1 : 2;
  const int WMR = SMALL ? 16 : 32;
  int frow = lane & 15, g = lane >> 4;
  f32x4 acc[2][2] = {};

  auto stage = [&](int buf, int k0){
    int e = tid;
    #pragma unroll
    for (int i = 0; i < 2; ++i, e += 256){     // A: 64x64 bf16 = 512 x 16B
      int row = e >> 3, cb = e & 7;
      gload16(A + (size_t)(m0+row)*K + k0 + ((cb ^ (row&7))<<3), &As[buf][e*8]);
    }
    e = tid;
    #pragma unroll
    for (int i = 0; i < (SMALL?1:2); ++i, e += 256){
      int row = e >> 3, cb = e & 7;
      gload16(Bw + (size_t)(n0+row)*K + k0 + ((cb ^ (row&7))<<3), &Bs[buf][e*8]);
    }
  };
  auto compute = [&](int buf){
    #pragma unroll
    for (int ks = 0; ks < 2; ++ks){
      bf16x8 af[2], bfv[2];
      #pragma unroll
      for (int fm = 0; fm < FM; ++fm){
        int ar = wr*WMR + fm*16 + frow;
        af[fm] = *(const bf16x8*)&As[buf][ar*64 + (((ks*4+g) ^ (ar&7))<<3)];
      }
      #pragma unroll
      for (int fn = 0; fn < 2; ++fn){
        int br = wc*32 + fn*16 + frow;
        bfv[fn] = *(const bf16x8*)&Bs[buf][br*64 + (((ks*4+g) ^ (br&7))<<3)];
      }
      #pragma unroll
      for (int fm = 0; fm < FM; ++fm)
        #pragma unroll
        for (int fn = 0; fn < 2; ++fn)
          acc[fm][fn] = __builtin_amdgcn_mfma_f32_16x16x32_bf16(af[fm], bfv[fn], acc[fm][fn], 0,0,0);
    }
  };

  stage(0, 0);
  __syncthreads();
  int cur = 0;
  for (int k0 = 64; k0 < K; k0 += 64){
    stage(cur^1, k0);          // prefetch next tile (loads fly during MFMA)
    compute(cur);
    __syncthreads();           // drains prefetch + protects LDS reuse
    cur ^= 1;
  }
  compute(cur);

  #pragma unroll
  for (int fm = 0; fm < FM; ++fm){
    #pragma unroll
    for (int fn = 0; fn < 2; ++fn){
      int n = n0 + wc*32 + fn*16 + frow;
      float bb = bias[n];
      int row0 = m0 + wr*WMR + fm*16 + g*4;
      if (epi == 3 && n >= 1024){
        int hh = (n-1024)>>5, dh = (n-1024)&31;
        int b = row0>>9, ll = row0&511;
        bf16x4 pv;
        #pragma unroll
        for (int i = 0; i < 4; ++i){
          float v = acc[fm][fn][i] + bb;
          outb[(size_t)(row0+i)*N + n] = (bf16_t)v;
          pv[i] = (bf16_t)v;
        }
        *(bf16x4*)&vT[(((size_t)(b*16+hh))*32 + dh)*512 + ll] = pv;
      } else {
        #pragma unroll
        for (int i = 0; i < 4; ++i){
          int row = row0 + i;
          float v = acc[fm][fn][i] + bb;
          if (epi == 1){
            v = res[(size_t)row*N + n] + te[(row>>9)*D_ + n] + gate[(size_t)row*gate_ld + n]*v;
            outf[(size_t)row*N + n] = v;
          } else if (epi == 2){
            outb[(size_t)row*N + n] = (bf16_t)geluf(v);
          } else if (epi == 3){
            outb[(size_t)row*N + n] = (bf16_t)v;
          } else if (epi == 4){
            v = res[(size_t)row*N + n] + gate[(size_t)row*gate_ld + n]*v;
            outf[(size_t)row*N + n] = v;
          } else {
            outf[(size_t)row*N + n] = v;
          }
        }
      }
    }
  }
}

// ---------------- MFMA attention: block = (b,h,16-row q-tile) ----------------
__global__ __launch_bounds__(256) void k_attn2(const bf16_t* __restrict__ qkv,
      const bf16_t* __restrict__ vT, const bf16_t* __restrict__ pfb,
      const float* __restrict__ keepf, bf16_t* __restrict__ obuf){
  __shared__ float ss[16][516];
  __shared__ float opart[4][16][33];
  __shared__ float inv_s[16];
  int blk = blockIdx.x;
  int qt = blk & 31;
  int bh = blk >> 5;
  int b = bh >> 4, h = bh & 15;
  int r0 = qt*16;
  int tid = threadIdx.x;
  int lane = tid & 63, w = tid >> 6;
  int frow = lane & 15, g = lane >> 4;
  const float scale = 0.17677669529663687f;  // 1/sqrt(32)
  bf16x8 qf = *(const bf16x8*)(qkv + (size_t)(b*512 + r0 + frow)*1536 + h*32 + g*8);
  // phase 1: S = QK^T*scale + pfb, masked; wave w covers k in [w*128, w*128+128)
  for (int t = 0; t < 8; ++t){
    int kc = w*128 + t*16;
    bf16x8 kf = *(const bf16x8*)(qkv + (size_t)(b*512 + kc + frow)*1536 + 512 + h*32 + g*8);
    f32x4 s4 = {};
    s4 = __builtin_amdgcn_mfma_f32_16x16x32_bf16(qf, kf, s4, 0,0,0);
    int tok = kc + frow;
    float kp = keepf[b*512 + tok];
    const bf16_t* pf = pfb + ((size_t)bh*512 + r0 + g*4)*512 + tok;
    #pragma unroll
    for (int i = 0; i < 4; ++i){
      float sv = s4[i]*scale + (float)pf[(size_t)i*512];
      sv = (kp == 0.f) ? -1e9f : sv;
      ss[g*4+i][tok] = sv;
    }
  }
  __syncthreads();
  // softmax (unnormalized e kept in ss; inv_s per row)
  {
    int r = tid >> 4, mo = tid & 15;
    float mx = -INFINITY;
    #pragma unroll 8
    for (int t2 = 0; t2 < 32; ++t2) mx = fmaxf(mx, ss[r][mo + 16*t2]);
    #pragma unroll
    for (int o = 1; o < 16; o <<= 1) mx = fmaxf(mx, __shfl_xor(mx, o));
    float sum = 0.f;
    #pragma unroll 8
    for (int t2 = 0; t2 < 32; ++t2){
      int m = mo + 16*t2;
      float e = __expf(ss[r][m] - mx);
      ss[r][m] = e;
      sum += e;
    }
    #pragma unroll
    for (int o = 1; o < 16; o <<= 1) sum += __shfl_xor(sum, o);
    if (mo == 0) inv_s[r] = 1.f/sum;
  }
  __syncthreads();
  // phase 2: O_partial = P[16, w-range] @ V[w-range, 32]
  f32x4 oacc[2] = {};
  for (int t = 0; t < 4; ++t){
    int kc = w*128 + t*32;
    float4 p0 = *(const float4*)&ss[frow][kc + g*8];
    float4 p1 = *(const float4*)&ss[frow][kc + g*8 + 4];
    bf16x8 pfr;
    pfr[0]=(bf16_t)p0.x; pfr[1]=(bf16_t)p0.y; pfr[2]=(bf16_t)p0.z; pfr[3]=(bf16_t)p0.w;
    pfr[4]=(bf16_t)p1.x; pfr[5]=(bf16_t)p1.y; pfr[6]=(bf16_t)p1.z; pfr[7]=(bf16_t)p1.w;
    #pragma unroll
    for (int fn = 0; fn < 2; ++fn){
      bf16x8 vf = *(const bf16x8*)(vT + ((size_t)bh*32 + fn*16 + frow)*512 + kc + g*8);
      oacc[fn] = __builtin_amdgcn_mfma_f32_16x16x32_bf16(pfr, vf, oacc[fn], 0,0,0);
    }
  }
  #pragma unroll
  for (int fn = 0; fn < 2; ++fn)
    #pragma unroll
    for (int i = 0; i < 4; ++i)
      opart[w][g*4+i][fn*16+frow] = oacc[fn][i];
  __syncthreads();
  // reduce over waves + normalize + write bf16
  {
    int q = tid >> 4, dh = (tid & 15)*2;
    float o0 = 0.f, o1 = 0.f;
    #pragma unroll
    for (int ww = 0; ww < 4; ++ww){ o0 += opart[ww][q][dh]; o1 += opart[ww][q][dh+1]; }
    float inv = inv_s[q];
    bf16x2 ov; ov[0] = (bf16_t)(o0*inv); ov[1] = (bf16_t)(o1*inv);
    *(bf16x2*)(obuf + (size_t)(b*512 + r0 + q)*512 + h*32 + dh) = ov;
  }
}

extern "C" void kernel_launch(void* const* d_in, const int* in_sizes, int n_in,
                              void* d_out, int out_size, void* d_ws, size_t ws_size,
                              hipStream_t stream){
  (void)in_sizes; (void)n_in; (void)out_size; (void)ws_size;
  const float* x        = (const float*)d_in[0];
  const float* pos      = (const float*)d_in[1];
  const float* time_emb = (const float*)d_in[2];
  const float* pair     = (const float*)d_in[3];
  const float* pos_w    = (const float*)d_in[4];
  const float* pfb_w    = (const float*)d_in[5];
  const float* p2n_w1   = (const float*)d_in[6];
  const float* p2n_w2   = (const float*)d_in[7];
  const float* adaln_w  = (const float*)d_in[8];
  const float* adaln_b  = (const float*)d_in[9];
  const float* qkv_w    = (const float*)d_in[10];
  const float* qkv_b    = (const float*)d_in[11];
  const float* proj_w   = (const float*)d_in[12];
  const float* proj_b   = (const float*)d_in[13];
  const float* mlp_w1   = (const float*)d_in[14];
  const float* mlp_b1   = (const float*)d_in[15];
  const float* mlp_w2   = (const float*)d_in[16];
  const float* mlp_b2   = (const float*)d_in[17];
  const int*   maskp    = (const int*)d_in[18];

  float* W = (float*)d_ws;
  size_t off = 0;
  auto alloc = [&](size_t nfw){ float* p = W + off; off += nfw; return p; };
  float*  h     = alloc(524288);
  float*  hin2  = alloc(524288);
  float*  modb  = alloc(6291456);            // [1024][6144] both layers
  float*  colm  = alloc(524288);
  float*  keepf = alloc(1024);
  bf16_t* pfbb  = (bf16_t*)alloc(4194304);   // 8,388,608 bf16
  bf16_t* condb = (bf16_t*)alloc(262144);    // 524,288 bf16
  bf16_t* abuf  = (bf16_t*)alloc(262144);    // 524,288 bf16
  bf16_t* qkvb  = (bf16_t*)alloc(786432);    // 1,572,864 bf16
  bf16_t* vTb   = (bf16_t*)alloc(262144);    // 524,288 bf16
  bf16_t* midb  = (bf16_t*)alloc(1048576);   // 2,097,152 bf16
  bf16_t* obuf  = (bf16_t*)alloc(262144);    // 524,288 bf16
  bf16_t* wB    = (bf16_t*)alloc(4718592);   // 9,437,184 bf16
  bf16_t* wA  = wB;                 // [2][3072][512]
  bf16_t* wQ  = wB + 3145728;
  bf16_t* wP  = wB + 4718592;
  bf16_t* wM1 = wB + 5242880;
  bf16_t* wM2 = wB + 7340032;

  // merged preamble: weight-cvt | posemb | pair-bias+colmean
  k_pre<<<NB_CVT + NB_POS + NT_*2, 256, 0, stream>>>(
      adaln_w, qkv_w, proj_w, mlp_w1, mlp_w2, wB,
      pos, pos_w, maskp, h, keepf,
      pair, pfb_w, pfbb, colm);
  k_topk_f2n<<<NT_, 128, 0, stream>>>(colm, pair, keepf, p2n_w1, p2n_w2, x, condb);
  // batched adaLN for BOTH layers: modb[1024][6144] = cond @ [2·3072,512]^T + b
  k_gemm_bf<false><<<dim3(96,16), 256, 0, stream>>>(condb, wA, adaln_b,
      NT_, 6144, 512, 0, modb, nullptr, nullptr, nullptr, 0, nullptr, nullptr);

  for (int l = 0; l < NL_; ++l){
    const float* modl = modb + (size_t)l*3072;
    // a = LN(h+te)*(1+sc_a)+sh_a -> bf16
    k_lnmod2<<<NT_, 128, 0, stream>>>(h, time_emb, modl, abuf, 0, 512, 6144);
    // qkv -> bf16 (+ vT)
    k_gemm_bf<false><<<dim3(24,16), 256, 0, stream>>>(abuf, wQ + (size_t)l*1536*512,
        qkv_b + (size_t)l*1536, NT_, 1536, 512, 3, nullptr, qkvb, nullptr, nullptr, 0, nullptr, vTb);
    k_attn2<<<B_*H_*32, 256, 0, stream>>>(qkvb, vTb, pfbb, keepf, obuf);
    // hin2 = (h+te) + g_a * (o@proj^T + b)
    k_gemm_bf<true><<<dim3(16,16), 256, 0, stream>>>(obuf, wP + (size_t)l*512*512,
        proj_b + (size_t)l*512, NT_, 512, 512, 1, hin2, nullptr, h,
        (const float*)(modl + 2*512), 6144, time_emb, nullptr);
    k_lnmod2<<<NT_, 128, 0, stream>>>(hin2, nullptr, modl, abuf, 3*512, 4*512, 6144);
    // mlp1 gelu -> bf16
    k_gemm_bf<false><<<dim3(32,16), 256, 0, stream>>>(abuf, wM1 + (size_t)l*2048*512,
        mlp_b1 + (size_t)l*2048, NT_, 2048, 512, 2, nullptr, midb, nullptr, nullptr, 0, nullptr, nullptr);
    // h_out = hin2 + g_m * (mid@mlp2^T + b)
    float* hout = (l == NL_-1) ? (float*)d_out : h;
    k_gemm_bf<true><<<dim3(16,16), 256, 0, stream>>>(midb, wM2 + (size_t)l*512*2048,
        mlp_b2 + (size_t)l*512, NT_, 512, 2048, 4, hout, nullptr, hin2,
        (const float*)(modl + 5*512), 6144, nullptr, nullptr);
  }
}